// Round 7
// baseline (332.172 us; speedup 1.0000x reference)
//
#include <hip/hip_runtime.h>
#include <stdint.h>

#define T_ 512
#define K_ 256
#define NB 16
#define WROW 264  // padded W row stride in ushorts (528 B)
#define L2E 1.4426950408889634f
#define LN2 0.6931471805599453f

typedef __attribute__((ext_vector_type(8))) short short8;
typedef __attribute__((ext_vector_type(4))) float f32x4;

__device__ __forceinline__ float fexp2(float x) {
#if __has_builtin(__builtin_amdgcn_exp2f)
  return __builtin_amdgcn_exp2f(x);
#else
  return exp2f(x);
#endif
}
__device__ __forceinline__ float flog2(float x) {
#if __has_builtin(__builtin_amdgcn_logf)
  return __builtin_amdgcn_logf(x);
#else
  return log2f(x);
#endif
}
__device__ __forceinline__ unsigned int umax_(unsigned int a, unsigned int b) {
  return a > b ? a : b;
}
__device__ __forceinline__ unsigned short f2bf(float f) {
  union { float f; uint32_t u; } v; v.f = f;
  uint32_t r = v.u + 0x7fffu + ((v.u >> 16) & 1u);
  return (unsigned short)(r >> 16);
}
// RNE pack of two f32 -> one dword of 2 bf16 (lo = a, hi = b)
__device__ __forceinline__ uint32_t cvt_pk_bf16(float a, float b) {
  uint32_t d;
  asm("v_cvt_pk_bf16_f32 %0, %1, %2" : "=v"(d) : "v"(a), "v"(b));
  return d;
}

// lgkm-only barrier: global loads stay in flight across it
#define BAR() do { \
  asm volatile("s_waitcnt lgkmcnt(0)" ::: "memory"); \
  __builtin_amdgcn_s_barrier(); \
  asm volatile("" ::: "memory"); \
} while (0)

// ---------- aux kernels (proven) ----------

__global__ void prep_E(const float* __restrict__ trans, unsigned short* __restrict__ Efrag) {
  int idx = blockIdx.x * 256 + threadIdx.x;  // 0..65535
  int e = idx & 7;
  int ln = (idx >> 3) & 63;
  int kb = (idx >> 9) & 7;
  int mt = idx >> 12;
  int j = mt * 16 + (ln & 15);
  int k = kb * 32 + ((ln >> 4) << 3) + e;
  Efrag[idx] = f2bf(__expf(trans[k * K_ + j]));
}

__global__ void aux_mask(const float* __restrict__ yp, unsigned char* __restrict__ masks) {
  int item = blockIdx.x * 4 + (threadIdx.x >> 6);  // b*512 + t
  int lane = threadIdx.x & 63;
  const float4 v = *(const float4*)(yp + (size_t)item * K_ + lane * 4);
  float mn = fminf(fminf(v.x, v.y), fminf(v.z, v.w));
  unsigned long long bl = __ballot(mn > -1000000.0f);
  if (lane == 0) {
    int b = item >> 9, t = item & 511;
    masks[t * 128 + b] = (bl == ~0ull) ? 1 : 0;
  }
}

__global__ void aux_score(const float* __restrict__ yp, const float* __restrict__ trans,
                          const int* __restrict__ ytrue, const unsigned char* __restrict__ masks,
                          float* __restrict__ score) {
  int b = blockIdx.x;
  int lane = threadIdx.x;  // 0..63
  float s = 0.f;
  #pragma unroll
  for (int k = 0; k < 8; ++k) {
    int t = lane + 64 * k;
    int y = ytrue[b * T_ + t];
    int m = masks[t * 128 + b];
    float x = yp[((size_t)b * T_ + t) * K_ + y];
    if (m) s += x;
    if (t >= 1) {
      int ym = ytrue[b * T_ + t - 1];
      int mm = masks[(t - 1) * 128 + b];
      if (m && mm) s += trans[ym * K_ + y];
    }
  }
  #pragma unroll
  for (int off = 32; off; off >>= 1) s += __shfl_xor(s, off, 64);
  if (lane == 0) score[b] = s;
}

// ---------- scan: 8 waves (2/SIMD), wave wv owns M-tiles {2wv, 2wv+1} ----------

template<int TM4, bool RESC, bool MWR, bool MASKED>
__device__ __forceinline__ void crf_step(
    int t, int c, int g, int wv, const int* tb,
    const short8 (&Ef)[2][8],
    float (&a)[8], float (&exf)[8], int& acc, int& mkc,
    const float* xb, float4 (&XN)[2], float4 (&XI)[2],
    unsigned short (*Wl)[NB * WROW], const unsigned char* mkl, unsigned int* Mpart) {
  BAR();
  // rescale (once per 4 steps, off the MFMA critical path)
  if (RESC) {
    unsigned int Mx = Mpart[c];
    #pragma unroll
    for (int w = 1; w < 8; ++w) Mx = umax_(Mx, Mpart[w * NB + c]);
    unsigned int e_ = Mx >> 23;
    float sf = __builtin_bit_cast(float, (254u - e_) << 23);
    if (!MASKED || mkc) acc += 127 - (int)e_;
    #pragma unroll
    for (int j = 0; j < 8; ++j) exf[j] *= sf;
  }
  // GEMM: S[tag][batch] = sum_i w[batch][i] * E[i][tag]
  // 8 independent depth-2 chains (4 accumulators per tile) to hide MFMA
  // dependency latency; tree-add tail.
  f32x4 ac0[4], ac1[4];
  #pragma unroll
  for (int q = 0; q < 4; ++q) {
    ac0[q] = (f32x4){0.f, 0.f, 0.f, 0.f};
    ac1[q] = (f32x4){0.f, 0.f, 0.f, 0.f};
  }
  {
    const unsigned short* rrow = &Wl[TM4 & 1][c * WROW];
    #pragma unroll
    for (int kb = 0; kb < 8; ++kb) {
      short8 bf = __builtin_bit_cast(short8, *(const uint4*)(&rrow[kb * 32 + g * 8]));
      ac0[kb & 3] = __builtin_amdgcn_mfma_f32_16x16x32_bf16(Ef[0][kb], bf, ac0[kb & 3], 0, 0, 0);
      ac1[kb & 3] = __builtin_amdgcn_mfma_f32_16x16x32_bf16(Ef[1][kb], bf, ac1[kb & 3], 0, 0, 0);
    }
  }
  f32x4 s0, s1;
  #pragma unroll
  for (int i = 0; i < 4; ++i) s0[i] = (ac0[0][i] + ac0[1][i]) + (ac0[2][i] + ac0[3][i]);
  #pragma unroll
  for (int i = 0; i < 4; ++i) s1[i] = (ac1[0][i] + ac1[1][i]) + (ac1[2][i] + ac1[3][i]);
  // alpha update
  if (MASKED) {
    #pragma unroll
    for (int i = 0; i < 4; ++i) { float an = s0[i] * exf[i];     a[i]     = mkc ? an : a[i]; }
    #pragma unroll
    for (int i = 0; i < 4; ++i) { float an = s1[i] * exf[4 + i]; a[4 + i] = mkc ? an : a[4 + i]; }
  } else {
    #pragma unroll
    for (int i = 0; i < 4; ++i) a[i]     = s0[i] * exf[i];
    #pragma unroll
    for (int i = 0; i < 4; ++i) a[4 + i] = s1[i] * exf[4 + i];
  }
  // pack alpha -> bf16 (RNE), write W[(t+1)&1]
  {
    unsigned short* wrow = &Wl[(TM4 + 1) & 1][c * WROW];
    #pragma unroll
    for (int m = 0; m < 2; ++m) {
      uint2 pp;
      pp.x = cvt_pk_bf16(a[4 * m + 0], a[4 * m + 1]);
      pp.y = cvt_pk_bf16(a[4 * m + 2], a[4 * m + 3]);
      *(uint2*)(&wrow[tb[m]]) = pp;
    }
  }
  // partial max of alpha for the next rescale
  if (MWR) {
    unsigned int pm = __builtin_bit_cast(uint32_t, a[0]);
    #pragma unroll
    for (int j = 1; j < 8; ++j) pm = umax_(pm, __builtin_bit_cast(uint32_t, a[j]));
    pm = umax_(pm, (unsigned int)__shfl_xor((int)pm, 16, 64));
    pm = umax_(pm, (unsigned int)__shfl_xor((int)pm, 32, 64));
    if (g == 0) Mpart[wv * NB + c] = pm;
  }
  // exf for step t+1 (slot XN loaded >= 3 steps ago)
  #pragma unroll
  for (int m = 0; m < 2; ++m) {
    exf[4 * m + 0] = fexp2(XN[m].x * L2E);
    exf[4 * m + 1] = fexp2(XN[m].y * L2E);
    exf[4 * m + 2] = fexp2(XN[m].z * L2E);
    exf[4 * m + 3] = fexp2(XN[m].w * L2E);
  }
  if (MASKED) mkc = mkl[(t + 1 < T_ ? t + 1 : 0) * NB + c];
  // issue x(t+4) into the just-freed slot
  {
    int tt = t + 4;
    tt = tt > (T_ - 1) ? (T_ - 1) : tt;
    #pragma unroll
    for (int m = 0; m < 2; ++m)
      XI[m] = *(const float4*)(xb + (size_t)tt * K_ + tb[m]);
  }
}

template<bool MASKED>
__device__ __forceinline__ void scan_run(
    int tid, int c, int g, int wv, const int* tb, int b0,
    const short8 (&Ef)[2][8], const float* xb,
    float4 (&xinit)[2], float4 (&X0q)[2], float4 (&X1q)[2],
    float4 (&X2q)[2], float4 (&X3q)[2],
    unsigned short (*Wl)[NB * WROW], const unsigned char* mkl,
    unsigned int* Mpart, float* Spart,
    const float* __restrict__ score, float* __restrict__ out) {
  float a[8], exf[8];
  int acc = 0;
  int mkc = 0;
  // alpha(0), linear domain
  {
    int mk0 = MASKED ? mkl[c] : 1;
    #pragma unroll
    for (int m = 0; m < 2; ++m) {
      float e0 = fexp2(xinit[m].x * L2E);
      float e1 = fexp2(xinit[m].y * L2E);
      float e2 = fexp2(xinit[m].z * L2E);
      float e3 = fexp2(xinit[m].w * L2E);
      a[4 * m + 0] = (MASKED && !mk0) ? 1.0f : e0;
      a[4 * m + 1] = (MASKED && !mk0) ? 1.0f : e1;
      a[4 * m + 2] = (MASKED && !mk0) ? 1.0f : e2;
      a[4 * m + 3] = (MASKED && !mk0) ? 1.0f : e3;
    }
  }
  // W[1] <- bf16(alpha(0))  (step t=1 reads parity 1)
  {
    unsigned short* wrow = &Wl[1][c * WROW];
    #pragma unroll
    for (int m = 0; m < 2; ++m) {
      uint2 pp;
      pp.x = cvt_pk_bf16(a[4 * m + 0], a[4 * m + 1]);
      pp.y = cvt_pk_bf16(a[4 * m + 2], a[4 * m + 3]);
      *(uint2*)(&wrow[tb[m]]) = pp;
    }
  }
  // exf(1) from X1q; mask(1)
  #pragma unroll
  for (int m = 0; m < 2; ++m) {
    exf[4 * m + 0] = fexp2(X1q[m].x * L2E);
    exf[4 * m + 1] = fexp2(X1q[m].y * L2E);
    exf[4 * m + 2] = fexp2(X1q[m].z * L2E);
    exf[4 * m + 3] = fexp2(X1q[m].w * L2E);
  }
  if (MASKED) mkc = mkl[NB + c];

  // prologue t = 1..3
  crf_step<1, false, false, MASKED>(1, c, g, wv, tb, Ef, a, exf, acc, mkc, xb, X2q, X1q, Wl, mkl, Mpart);
  crf_step<2, false, false, MASKED>(2, c, g, wv, tb, Ef, a, exf, acc, mkc, xb, X3q, X2q, Wl, mkl, Mpart);
  crf_step<3, false, true , MASKED>(3, c, g, wv, tb, Ef, a, exf, acc, mkc, xb, X0q, X3q, Wl, mkl, Mpart);

  #pragma unroll 1
  for (int t0 = 4; t0 < T_; t0 += 4) {
    crf_step<0, true , false, MASKED>(t0,     c, g, wv, tb, Ef, a, exf, acc, mkc, xb, X1q, X0q, Wl, mkl, Mpart);
    crf_step<1, false, false, MASKED>(t0 + 1, c, g, wv, tb, Ef, a, exf, acc, mkc, xb, X2q, X1q, Wl, mkl, Mpart);
    crf_step<2, false, false, MASKED>(t0 + 2, c, g, wv, tb, Ef, a, exf, acc, mkc, xb, X3q, X2q, Wl, mkl, Mpart);
    crf_step<3, false, true , MASKED>(t0 + 3, c, g, wv, tb, Ef, a, exf, acc, mkc, xb, X0q, X3q, Wl, mkl, Mpart);
  }

  // final: out = ln2*(log2(sum alpha) - acc) - score
  __syncthreads();
  {
    float ssum = 0.f;
    #pragma unroll
    for (int j = 0; j < 8; ++j) ssum += a[j];
    ssum += __shfl_xor(ssum, 16, 64);
    ssum += __shfl_xor(ssum, 32, 64);
    if (g == 0) Spart[wv * NB + c] = ssum;
  }
  __syncthreads();
  if (tid < NB) {
    float S = 0.f;
    #pragma unroll
    for (int w = 0; w < 8; ++w) S += Spart[w * NB + tid];
    out[b0 + tid] = LN2 * (flog2(S) - (float)acc) - score[b0 + tid];
  }
}

__global__ __launch_bounds__(512, 1) void crf_scan(
    const float* __restrict__ yp, const unsigned short* __restrict__ Efrag,
    const unsigned char* __restrict__ masks, const float* __restrict__ score,
    float* __restrict__ out) {
  const int b0 = blockIdx.x * NB;
  const int tid = threadIdx.x;
  const int wv = tid >> 6, lane = tid & 63;
  const int c = lane & 15;       // batch column
  const int g = lane >> 4;       // k-group / row-group

  __shared__ unsigned short Wl[2][NB * WROW];  // ~16.9 KB
  __shared__ unsigned char mkl[T_ * NB];       // 8 KB
  __shared__ unsigned int Mpart[8 * NB];
  __shared__ float Spart[8 * NB];
  __shared__ int sflag[8];

  // E fragments -> registers: wave wv owns M-tiles {2wv, 2wv+1} (32 VGPR)
  short8 Ef[2][8];
  {
    const uint4* ep = (const uint4*)Efrag;
    #pragma unroll
    for (int m = 0; m < 2; ++m)
      #pragma unroll
      for (int kb = 0; kb < 8; ++kb)
        Ef[m][kb] = __builtin_bit_cast(short8, ep[((wv * 2 + m) * 8 + kb) * 64 + lane]);
  }

  // mask table -> LDS (mkl[t*16 + c]); also all-ones check
  uint4 md0;
  {
    uint4* dst = (uint4*)mkl;
    md0 = *(const uint4*)(masks + tid * 128 + b0);
    dst[tid] = md0;
  }

  const float* xb = yp + (size_t)(b0 + c) * T_ * K_;
  int tb[2];
  #pragma unroll
  for (int m = 0; m < 2; ++m) tb[m] = wv * 32 + m * 16 + g * 4;

  float4 xinit[2], X0q[2], X1q[2], X2q[2], X3q[2];
  #pragma unroll
  for (int m = 0; m < 2; ++m) xinit[m] = *(const float4*)(xb + tb[m]);
  #pragma unroll
  for (int m = 0; m < 2; ++m) X1q[m] = *(const float4*)(xb + 1 * K_ + tb[m]);
  #pragma unroll
  for (int m = 0; m < 2; ++m) X2q[m] = *(const float4*)(xb + 2 * K_ + tb[m]);
  #pragma unroll
  for (int m = 0; m < 2; ++m) X3q[m] = *(const float4*)(xb + 3 * K_ + tb[m]);
  #pragma unroll
  for (int m = 0; m < 2; ++m) X0q[m] = *(const float4*)(xb + 4 * K_ + tb[m]);

  // all-masks-one check (block-uniform)
  {
    uint32_t w = md0.x & md0.y & md0.z & md0.w;
    unsigned long long bl = __ballot(w == 0x01010101u);
    if (lane == 0) sflag[wv] = (bl == ~0ull) ? 1 : 0;
  }
  __syncthreads();
  bool allm = true;
  #pragma unroll
  for (int w = 0; w < 8; ++w) allm = allm && sflag[w];

  if (allm) {
    scan_run<false>(tid, c, g, wv, tb, b0, Ef, xb, xinit, X0q, X1q, X2q, X3q,
                    Wl, mkl, Mpart, Spart, score, out);
  } else {
    scan_run<true>(tid, c, g, wv, tb, b0, Ef, xb, xinit, X0q, X1q, X2q, X3q,
                   Wl, mkl, Mpart, Spart, score, out);
  }
}

extern "C" void kernel_launch(void* const* d_in, const int* in_sizes, int n_in,
                              void* d_out, int out_size, void* d_ws, size_t ws_size,
                              hipStream_t stream) {
  const float* yp = (const float*)d_in[0];
  const float* trans = (const float*)d_in[1];
  const int* ytrue = (const int*)d_in[2];
  float* out = (float*)d_out;

  unsigned short* Efrag = (unsigned short*)d_ws;                 // 128 KB
  unsigned char* masks = (unsigned char*)d_ws + 131072;          // 64 KB
  float* score = (float*)((char*)d_ws + 131072 + 65536);         // 512 B

  prep_E<<<dim3(256), dim3(256), 0, stream>>>(trans, Efrag);
  aux_mask<<<dim3(16384), dim3(256), 0, stream>>>(yp, masks);
  aux_score<<<dim3(128), dim3(64), 0, stream>>>(yp, trans, ytrue, masks, score);
  crf_scan<<<dim3(8), dim3(512), 0, stream>>>(yp, Efrag, masks, score, out);
}

// Round 10
// 320.965 us; speedup vs baseline: 1.0349x; 1.0349x over previous
//
#include <hip/hip_runtime.h>
#include <stdint.h>

#define T_ 512
#define K_ 256
#define NB 16
#define WSTRIDE 272  // fp8 W row stride in BYTES (256 + 16 pad)
#define L2E 1.4426950408889634f
#define LN2 0.6931471805599453f

typedef __attribute__((ext_vector_type(4))) float f32x4;

__device__ __forceinline__ float fexp2(float x) {
#if __has_builtin(__builtin_amdgcn_exp2f)
  return __builtin_amdgcn_exp2f(x);
#else
  return exp2f(x);
#endif
}
__device__ __forceinline__ float flog2(float x) {
#if __has_builtin(__builtin_amdgcn_logf)
  return __builtin_amdgcn_logf(x);
#else
  return log2f(x);
#endif
}
__device__ __forceinline__ unsigned int umax_(unsigned int a, unsigned int b) {
  return a > b ? a : b;
}
__device__ __forceinline__ float bits2f(uint32_t u) { return __builtin_bit_cast(float, u); }
__device__ __forceinline__ uint32_t f2bits(float f) { return __builtin_bit_cast(uint32_t, f); }

// RNE pack of two f32 -> one dword of 2 bf16 (lo = a, hi = b)
__device__ __forceinline__ uint32_t cvt_pk_bf16(float a, float b) {
  uint32_t d;
  asm("v_cvt_pk_bf16_f32 %0, %1, %2" : "=v"(d) : "v"(a), "v"(b));
  return d;
}

// pack two positive floats to bf8 (OCP e5m2) into lo/hi half of a dword.
// HI is a compile-time constant (encodes as op_sel).
template<bool HI>
__device__ __forceinline__ uint32_t pk_bf8(float a, float b, uint32_t old) {
#if __has_builtin(__builtin_amdgcn_cvt_pk_bf8_f32)
  return (uint32_t)__builtin_amdgcn_cvt_pk_bf8_f32(a, b, (int)old, HI);
#else
  unsigned short ha = __builtin_bit_cast(unsigned short, (_Float16)fminf(a, 57344.0f));
  unsigned short hb = __builtin_bit_cast(unsigned short, (_Float16)fminf(b, 57344.0f));
  uint32_t ra = (((uint32_t)ha + 0x7Fu + ((ha >> 8) & 1u)) >> 8) & 0xFFu;
  uint32_t rb = (((uint32_t)hb + 0x7Fu + ((hb >> 8) & 1u)) >> 8) & 0xFFu;
  uint32_t v = ra | (rb << 8);
  return HI ? ((old & 0x0000FFFFu) | (v << 16)) : ((old & 0xFFFF0000u) | v);
#endif
}

// f32 (positive) -> OCP e4m3fn byte, RNE
__device__ unsigned char to_e4m3(float f) {
  if (!(f > 0.0f)) return 0;
  if (f >= 448.0f) return 0x7E;
  uint32_t u = f2bits(f);
  int e = (int)((u >> 23) & 255) - 127;
  uint32_t m = u & 0x7fffff;
  if (e < -6) {
    int s2 = 20 + (-6 - e);
    if (s2 >= 24) return 0;
    uint32_t full = 0x800000u | m;
    uint32_t q = full >> s2, r = full & ((1u << s2) - 1);
    uint32_t half = 1u << (s2 - 1);
    q += (r > half || (r == half && (q & 1))) ? 1u : 0u;
    return (unsigned char)q;
  }
  uint32_t q = m >> 20, r = m & 0xFFFFFu;
  q += (r > 0x80000u || (r == 0x80000u && (q & 1))) ? 1u : 0u;
  if (q == 8) { q = 0; e += 1; if (e > 8) return 0x7E; }
  return (unsigned char)(((e + 7) << 3) | q);
}

// lgkm-only barrier: global loads stay in flight across it
#define BAR() do { \
  asm volatile("s_waitcnt lgkmcnt(0)" ::: "memory"); \
  __builtin_amdgcn_s_barrier(); \
  asm volatile("" ::: "memory"); \
} while (0)

// ---------- aux kernels ----------

__global__ void prep_E(const float* __restrict__ trans, unsigned char* __restrict__ Efrag) {
  int idx = blockIdx.x * 256 + threadIdx.x;  // 0..65535
  int e = idx & 7;
  int ln = (idx >> 3) & 63;
  int kb = (idx >> 9) & 7;
  int mt = idx >> 12;
  int j = mt * 16 + (ln & 15);
  int k = kb * 32 + ((ln >> 4) << 3) + e;
  Efrag[idx] = to_e4m3(__expf(trans[k * K_ + j]));
}

__global__ void aux_mask_exf(const float* __restrict__ yp, unsigned char* __restrict__ masks,
                             unsigned short* __restrict__ exf, int write_exf) {
  int item = blockIdx.x * 4 + (threadIdx.x >> 6);  // b*512 + t
  int lane = threadIdx.x & 63;
  const float4 v = *(const float4*)(yp + (size_t)item * K_ + lane * 4);
  float mn = fminf(fminf(v.x, v.y), fminf(v.z, v.w));
  unsigned long long bl = __ballot(mn > -1000000.0f);
  if (lane == 0) {
    int b = item >> 9, t = item & 511;
    masks[t * 128 + b] = (bl == ~0ull) ? 1 : 0;
  }
  if (write_exf) {
    uint2 p;
    p.x = cvt_pk_bf16(fexp2(v.x * L2E), fexp2(v.y * L2E));
    p.y = cvt_pk_bf16(fexp2(v.z * L2E), fexp2(v.w * L2E));
    *(uint2*)(exf + (size_t)item * K_ + lane * 4) = p;
  }
}

__global__ void aux_score(const float* __restrict__ yp, const float* __restrict__ trans,
                          const int* __restrict__ ytrue, const unsigned char* __restrict__ masks,
                          float* __restrict__ score) {
  int b = blockIdx.x;
  int lane = threadIdx.x;  // 0..63
  float s = 0.f;
  #pragma unroll
  for (int k = 0; k < 8; ++k) {
    int t = lane + 64 * k;
    int y = ytrue[b * T_ + t];
    int m = masks[t * 128 + b];
    float x = yp[((size_t)b * T_ + t) * K_ + y];
    if (m) s += x;
    if (t >= 1) {
      int ym = ytrue[b * T_ + t - 1];
      int mm = masks[(t - 1) * 128 + b];
      if (m && mm) s += trans[ym * K_ + y];
    }
  }
  #pragma unroll
  for (int off = 32; off; off >>= 1) s += __shfl_xor(s, off, 64);
  if (lane == 0) score[b] = s;
}

// ---------- scan ----------

template<bool PRE> struct Slot;
template<> struct Slot<true>  { uint2 u0, u1; };    // 8 bf16 exp(x)
template<> struct Slot<false> { float4 f0, f1; };   // 8 f32 x

template<bool PRE>
__device__ __forceinline__ void slot_load(Slot<PRE>& s, const void* base, int tt, int off0) {
  if constexpr (PRE) {
    const unsigned short* p = (const unsigned short*)base + (size_t)tt * K_ + off0;
    s.u0 = *(const uint2*)(p);
    s.u1 = *(const uint2*)(p + 16);
  } else {
    const float* p = (const float*)base + (size_t)tt * K_ + off0;
    s.f0 = *(const float4*)(p);
    s.f1 = *(const float4*)(p + 16);
  }
}

template<bool PRE>
__device__ __forceinline__ void slot_exf(const Slot<PRE>& s, float (&exf)[8]) {
  if constexpr (PRE) {
    exf[0] = bits2f(s.u0.x << 16); exf[1] = bits2f(s.u0.x & 0xffff0000u);
    exf[2] = bits2f(s.u0.y << 16); exf[3] = bits2f(s.u0.y & 0xffff0000u);
    exf[4] = bits2f(s.u1.x << 16); exf[5] = bits2f(s.u1.x & 0xffff0000u);
    exf[6] = bits2f(s.u1.y << 16); exf[7] = bits2f(s.u1.y & 0xffff0000u);
  } else {
    exf[0] = fexp2(s.f0.x * L2E); exf[1] = fexp2(s.f0.y * L2E);
    exf[2] = fexp2(s.f0.z * L2E); exf[3] = fexp2(s.f0.w * L2E);
    exf[4] = fexp2(s.f1.x * L2E); exf[5] = fexp2(s.f1.y * L2E);
    exf[6] = fexp2(s.f1.z * L2E); exf[7] = fexp2(s.f1.w * L2E);
  }
}

// Pack 8 stored-alpha values (clamped) to bf8 and store to this thread's W row.
__device__ __forceinline__ void pack_w(const float (&a)[8], unsigned char* wrow, int wv, int g) {
  float s0 = fminf(a[0], 57344.f), s1 = fminf(a[1], 57344.f);
  float s2 = fminf(a[2], 57344.f), s3 = fminf(a[3], 57344.f);
  float s4 = fminf(a[4], 57344.f), s5 = fminf(a[5], 57344.f);
  float s6 = fminf(a[6], 57344.f), s7 = fminf(a[7], 57344.f);
  uint32_t u0 = pk_bf8<false>(s0, s1, 0u); u0 = pk_bf8<true>(s2, s3, u0);
  uint32_t u1 = pk_bf8<false>(s4, s5, 0u); u1 = pk_bf8<true>(s6, s7, u1);
  *(uint32_t*)(wrow + 32 * wv + 4 * g) = u0;
  *(uint32_t*)(wrow + 32 * wv + 16 + 4 * g) = u1;
}

template<int TM4, bool MASKED, bool PRE>
__device__ __forceinline__ void crf_step(
    int t, int c, int g, int wv, int off0,
    const uint2 (&Ef)[2][8],
    float (&a)[8], float (&exf)[8], int& acc, int& mkc,
    const void* xbase, Slot<PRE>& XN, Slot<PRE>& XI,
    unsigned char (*Wl)[NB * WSTRIDE], const unsigned char* mkl,
    unsigned int (*Mpart)[NB][8]) {
  BAR();
  // fresh per-batch max of stored alpha(t-1) -> this step's normalization
  unsigned int Mx;
  {
    const uint4* mp = (const uint4*)&Mpart[(TM4 + 1) & 1][c][0];
    uint4 m0 = mp[0], m1 = mp[1];
    Mx = umax_(umax_(umax_(m0.x, m0.y), umax_(m0.z, m0.w)),
               umax_(umax_(m1.x, m1.y), umax_(m1.z, m1.w)));
  }
  unsigned int e_ = Mx >> 23;
  float sfp = bits2f((248u - e_) << 23);  // 2^(-6 - (e_-127))
  int scur = 121 - (int)e_;
  // MFMA: S[tag][batch] = sum_i E[i][tag] * w[batch][i]
  f32x4 ac0 = {0.f, 0.f, 0.f, 0.f}, ac1 = {0.f, 0.f, 0.f, 0.f};
  {
    const unsigned char* rrow = &Wl[TM4 & 1][c * WSTRIDE];
    #pragma unroll
    for (int kb = 0; kb < 8; ++kb) {
      long bf = *(const long*)(rrow + kb * 32 + g * 8);
      ac0 = __builtin_amdgcn_mfma_f32_16x16x32_fp8_bf8(
          __builtin_bit_cast(long, Ef[0][kb]), bf, ac0, 0, 0, 0);
      ac1 = __builtin_amdgcn_mfma_f32_16x16x32_fp8_bf8(
          __builtin_bit_cast(long, Ef[1][kb]), bf, ac1, 0, 0, 0);
    }
  }
  // alpha update with folded-in normalization: a = (ac*exf)*sfp
  if (MASKED) {
    #pragma unroll
    for (int i = 0; i < 4; ++i) { float an = ac0[i] * exf[i] * sfp;     a[i]     = mkc ? an : a[i]; }
    #pragma unroll
    for (int i = 0; i < 4; ++i) { float an = ac1[i] * exf[4 + i] * sfp; a[4 + i] = mkc ? an : a[4 + i]; }
    if (mkc) acc += scur;
  } else {
    #pragma unroll
    for (int i = 0; i < 4; ++i) a[i]     = ac0[i] * exf[i] * sfp;
    #pragma unroll
    for (int i = 0; i < 4; ++i) a[4 + i] = ac1[i] * exf[4 + i] * sfp;
    acc += scur;
  }
  // pack stored alpha -> bf8 (clamped), write W[(t+1)&1]
  pack_w(a, &Wl[(TM4 + 1) & 1][c * WSTRIDE], wv, g);
  // per-batch partial max of stored alpha for the NEXT step's normalization
  {
    unsigned int pm = f2bits(a[0]);
    #pragma unroll
    for (int j = 1; j < 8; ++j) pm = umax_(pm, f2bits(a[j]));
    pm = umax_(pm, (unsigned int)__shfl_xor((int)pm, 16, 64));
    pm = umax_(pm, (unsigned int)__shfl_xor((int)pm, 32, 64));
    if (g == 0) Mpart[TM4 & 1][c][wv] = pm;
  }
  // exf for step t+1 (slot loaded >= 3 steps ago)
  slot_exf<PRE>(XN, exf);
  if (MASKED) mkc = mkl[(t + 1 < T_ ? t + 1 : 0) * NB + c];
  // issue loads for t+4 into the just-freed slot
  {
    int tt = t + 4;
    tt = tt > (T_ - 1) ? (T_ - 1) : tt;
    slot_load<PRE>(XI, xbase, tt, off0);
  }
}

template<bool MASKED, bool PRE>
__device__ __forceinline__ void scan_run(
    int tid, int c, int g, int wv, int off0, int b0,
    const uint2 (&Ef)[2][8], const void* xbase,
    Slot<PRE>& Sinit, Slot<PRE>& S0, Slot<PRE>& S1, Slot<PRE>& S2, Slot<PRE>& S3,
    unsigned char (*Wl)[NB * WSTRIDE], const unsigned char* mkl,
    unsigned int (*Mpart)[NB][8], float* Spart,
    const float* __restrict__ score, float* __restrict__ out) {
  float a[8], exf[8];
  int acc = 0, mkc = 0;
  // alpha(0), linear domain
  {
    float e0[8];
    slot_exf<PRE>(Sinit, e0);
    int mk0 = MASKED ? mkl[c] : 1;
    #pragma unroll
    for (int j = 0; j < 8; ++j) a[j] = (MASKED && !mk0) ? 1.0f : e0[j];
  }
  // pre-scale per-wave partial max of a(0)
  unsigned int pm0;
  {
    unsigned int pm = f2bits(a[0]);
    #pragma unroll
    for (int j = 1; j < 8; ++j) pm = umax_(pm, f2bits(a[j]));
    pm = umax_(pm, (unsigned int)__shfl_xor((int)pm, 16, 64));
    pm = umax_(pm, (unsigned int)__shfl_xor((int)pm, 32, 64));
    pm0 = pm;
    if (g == 0) Mpart[0][c][wv] = pm;
  }
  __syncthreads();
  // exact scale for a(0)
  float sfp0;
  {
    unsigned int Mx;
    const uint4* mp = (const uint4*)&Mpart[0][c][0];
    uint4 m0 = mp[0], m1 = mp[1];
    Mx = umax_(umax_(umax_(m0.x, m0.y), umax_(m0.z, m0.w)),
               umax_(umax_(m1.x, m1.y), umax_(m1.z, m1.w)));
    unsigned int e_ = Mx >> 23;
    sfp0 = bits2f((248u - e_) << 23);
    acc = 121 - (int)e_;
  }
  __syncthreads();  // all Mx reads done before re-publish
  #pragma unroll
  for (int j = 0; j < 8; ++j) a[j] *= sfp0;
  // re-publish SCALED partial max (visible to step 1 via its BAR)
  if (g == 0) Mpart[0][c][wv] = f2bits(bits2f(pm0) * sfp0);
  // pack W[1] = bf8(stored alpha(0))
  pack_w(a, &Wl[1][c * WSTRIDE], wv, g);
  slot_exf<PRE>(S1, exf);  // exf(1)
  if (MASKED) mkc = mkl[NB + c];

  // prologue t = 1..3
  crf_step<1, MASKED, PRE>(1, c, g, wv, off0, Ef, a, exf, acc, mkc, xbase, S2, S1, Wl, mkl, Mpart);
  crf_step<2, MASKED, PRE>(2, c, g, wv, off0, Ef, a, exf, acc, mkc, xbase, S3, S2, Wl, mkl, Mpart);
  crf_step<3, MASKED, PRE>(3, c, g, wv, off0, Ef, a, exf, acc, mkc, xbase, S0, S3, Wl, mkl, Mpart);

  #pragma unroll 1
  for (int t0 = 4; t0 < T_; t0 += 4) {
    crf_step<0, MASKED, PRE>(t0,     c, g, wv, off0, Ef, a, exf, acc, mkc, xbase, S1, S0, Wl, mkl, Mpart);
    crf_step<1, MASKED, PRE>(t0 + 1, c, g, wv, off0, Ef, a, exf, acc, mkc, xbase, S2, S1, Wl, mkl, Mpart);
    crf_step<2, MASKED, PRE>(t0 + 2, c, g, wv, off0, Ef, a, exf, acc, mkc, xbase, S3, S2, Wl, mkl, Mpart);
    crf_step<3, MASKED, PRE>(t0 + 3, c, g, wv, off0, Ef, a, exf, acc, mkc, xbase, S0, S3, Wl, mkl, Mpart);
  }

  // final: out = ln2*(log2(sum stored) - acc) - score
  __syncthreads();
  {
    float ssum = 0.f;
    #pragma unroll
    for (int j = 0; j < 8; ++j) ssum += a[j];
    ssum += __shfl_xor(ssum, 16, 64);
    ssum += __shfl_xor(ssum, 32, 64);
    if (g == 0) Spart[wv * NB + c] = ssum;
  }
  __syncthreads();
  if (tid < NB) {
    float S = 0.f;
    #pragma unroll
    for (int w = 0; w < 8; ++w) S += Spart[w * NB + tid];
    out[b0 + tid] = LN2 * (flog2(S) - (float)acc) - score[b0 + tid];
  }
}

template<bool PRE>
__global__ __launch_bounds__(512, 1) void crf_scan(
    const float* __restrict__ yp, const unsigned char* __restrict__ Efrag,
    const unsigned char* __restrict__ masks, const unsigned short* __restrict__ exfp,
    const float* __restrict__ score, float* __restrict__ out) {
  const int b0 = blockIdx.x * NB;
  const int tid = threadIdx.x;
  const int wv = tid >> 6, lane = tid & 63;
  const int c = lane & 15;   // batch column
  const int g = lane >> 4;   // k-group / row-group
  const int off0 = 32 * wv + 4 * g;  // this thread's first tag

  __shared__ unsigned char Wl[2][NB * WSTRIDE];  // 8.5 KB
  __shared__ unsigned char mkl[T_ * NB];         // 8 KB
  __shared__ unsigned int Mpart[2][NB][8];       // 1 KB
  __shared__ float Spart[8 * NB];
  __shared__ int sflag[8];

  // E fragments (fp8): wave wv owns M-tiles {2wv, 2wv+1}
  uint2 Ef[2][8];
  {
    const uint2* ep = (const uint2*)Efrag;
    #pragma unroll
    for (int m = 0; m < 2; ++m)
      #pragma unroll
      for (int kb = 0; kb < 8; ++kb)
        Ef[m][kb] = ep[((wv * 2 + m) * 8 + kb) * 64 + lane];
  }

  // mask table -> LDS (mkl[t*16 + c]); all-ones check
  uint4 md0;
  {
    uint4* dst = (uint4*)mkl;
    md0 = *(const uint4*)(masks + tid * 128 + b0);
    dst[tid] = md0;
  }

  const void* xbase;
  if constexpr (PRE) xbase = (const void*)(exfp + (size_t)(b0 + c) * T_ * K_);
  else               xbase = (const void*)(yp + (size_t)(b0 + c) * T_ * K_);

  Slot<PRE> Sinit, S0, S1, S2, S3;
  slot_load<PRE>(Sinit, xbase, 0, off0);
  slot_load<PRE>(S1, xbase, 1, off0);
  slot_load<PRE>(S2, xbase, 2, off0);
  slot_load<PRE>(S3, xbase, 3, off0);
  slot_load<PRE>(S0, xbase, 4, off0);

  // all-masks-one check (block-uniform)
  {
    uint32_t w = md0.x & md0.y & md0.z & md0.w;
    unsigned long long bl = __ballot(w == 0x01010101u);
    if (lane == 0) sflag[wv] = (bl == ~0ull) ? 1 : 0;
  }
  __syncthreads();
  bool allm = true;
  #pragma unroll
  for (int w = 0; w < 8; ++w) allm = allm && sflag[w];

  if (allm) {
    scan_run<false, PRE>(tid, c, g, wv, off0, b0, Ef, xbase, Sinit, S0, S1, S2, S3,
                         Wl, mkl, Mpart, Spart, score, out);
  } else {
    scan_run<true, PRE>(tid, c, g, wv, off0, b0, Ef, xbase, Sinit, S0, S1, S2, S3,
                        Wl, mkl, Mpart, Spart, score, out);
  }
}

extern "C" void kernel_launch(void* const* d_in, const int* in_sizes, int n_in,
                              void* d_out, int out_size, void* d_ws, size_t ws_size,
                              hipStream_t stream) {
  const float* yp = (const float*)d_in[0];
  const float* trans = (const float*)d_in[1];
  const int* ytrue = (const int*)d_in[2];
  float* out = (float*)d_out;

  unsigned char* Efrag = (unsigned char*)d_ws;                  // 64 KB
  unsigned char* masks = (unsigned char*)d_ws + 65536;          // 64 KB
  float* score = (float*)((char*)d_ws + 131072);                // 512 B
  unsigned short* exf = (unsigned short*)((char*)d_ws + 131584);  // 32 MB (optional)

  const size_t exf_bytes = (size_t)128 * T_ * K_ * sizeof(unsigned short);
  const bool pre = ws_size >= 131584 + exf_bytes;

  prep_E<<<dim3(256), dim3(256), 0, stream>>>(trans, Efrag);
  aux_mask_exf<<<dim3(16384), dim3(256), 0, stream>>>(yp, masks, exf, pre ? 1 : 0);
  aux_score<<<dim3(128), dim3(64), 0, stream>>>(yp, trans, ytrue, masks, score);
  if (pre) {
    crf_scan<true><<<dim3(8), dim3(512), 0, stream>>>(yp, Efrag, masks, exf, score, out);
  } else {
    crf_scan<false><<<dim3(8), dim3(512), 0, stream>>>(yp, Efrag, masks, exf, score, out);
  }
}